// Round 4
// baseline (36275.848 us; speedup 1.0000x reference)
//
#include <hip/hip_runtime.h>
#include <math.h>
#include <stdint.h>

// BiLSTMModel: char-LSTM (GEMM-shaped) -> 2x BiLSTM scans (latency-bound) -> FCs.
// Scan v4: one WAVE per WG (64 thr), 2 hidden units/WG, 256 WGs/dir, grid 512.
// No LDS, no barriers. Each lane polls a disjoint 64B ring slice (4x dwordx4
// sc0sc1 in one asm block, single vmcnt(0)), 64 FMAs (8 indep chains), wave
// butterfly reduce, lanes 0/1 do nonlinearity + publish {h,tag} 8B words.
// 2-slot ring provably safe: every WG consumes every word each step.

#define NPOS 4096
#define GDIM 2048   // 4*H

typedef unsigned int uint4v __attribute__((ext_vector_type(4)));

__device__ __forceinline__ float sigf(float x) { return 1.0f / (1.0f + __expf(-x)); }
__device__ __forceinline__ float tanh_fast(float x) {
  float e = __expf(2.f * x);
  return 1.f - 2.f / (e + 1.f);   // exact at +-inf, NaN-free
}

// ---------------- build transposed concat char weight: Wt[k][g]
__global__ __launch_bounds__(256) void build_wt_kernel(
    const float* __restrict__ cWih, const float* __restrict__ cWhh,
    float* __restrict__ Wt)
{
  __shared__ float tile[64][65];
  const int k0 = blockIdx.x * 64;
  const int g0 = blockIdx.y * 64;
  const float* src = (k0 < 256) ? cWih : cWhh;
  const int sk0 = k0 & 255;
  for (int i = threadIdx.x; i < 64 * 64; i += 256) {
    int r = i >> 6, cc = i & 63;
    tile[r][cc] = src[(size_t)(g0 + r) * 256 + sk0 + cc];
  }
  __syncthreads();
  for (int i = threadIdx.x; i < 64 * 64; i += 256) {
    int kk = i >> 6, gg = i & 63;
    Wt[(size_t)(k0 + kk) * 1024 + g0 + gg] = tile[gg][kk];
  }
}

// ---------------- char LSTM: 256 blocks x 16 words, thread = channel
__global__ __launch_bounds__(256) void char_lstm_kernel(
    const int* __restrict__ chars, const int* __restrict__ lens,
    const float* __restrict__ table, const float* __restrict__ Wt,
    const float* __restrict__ cb, float* __restrict__ word_emb)
{
  __shared__ float u[16][512];
  __shared__ float wt[8][1024];
  __shared__ int sidx[16];
  const int tid = threadIdx.x;
  const int ch = tid;
  const int w0 = blockIdx.x * 16;
  if (tid < 16) { int l = lens[w0 + tid]; sidx[tid] = (l < 1 ? 1 : l) - 1; }
  float c[16], acc0[16], acc1[16], acc2[16], acc3[16];
  #pragma unroll
  for (int w = 0; w < 16; ++w) { u[w][256 + ch] = 0.f; c[w] = 0.f; }
  const float cb0 = cb[ch], cb1 = cb[256 + ch], cb2 = cb[512 + ch], cb3 = cb[768 + ch];

  for (int t = 0; t < 16; ++t) {
    for (int w = 0; w < 16; ++w) {
      int cid = chars[(w0 + w) * 16 + t];
      u[w][ch] = table[(size_t)cid * 256 + ch];
    }
    #pragma unroll
    for (int w = 0; w < 16; ++w) { acc0[w] = cb0; acc1[w] = cb1; acc2[w] = cb2; acc3[w] = cb3; }
    for (int k0 = 0; k0 < 512; k0 += 8) {
      #pragma unroll
      for (int r = 0; r < 8; ++r)
        ((float4*)&wt[r][0])[tid] = ((const float4*)(Wt + (size_t)(k0 + r) * 1024))[tid];
      __syncthreads();
      #pragma unroll
      for (int kk = 0; kk < 8; ++kk) {
        const float wv0 = wt[kk][ch], wv1 = wt[kk][256 + ch];
        const float wv2 = wt[kk][512 + ch], wv3 = wt[kk][768 + ch];
        #pragma unroll
        for (int w = 0; w < 16; ++w) {
          const float uv = u[w][k0 + kk];
          acc0[w] = fmaf(wv0, uv, acc0[w]);
          acc1[w] = fmaf(wv1, uv, acc1[w]);
          acc2[w] = fmaf(wv2, uv, acc2[w]);
          acc3[w] = fmaf(wv3, uv, acc3[w]);
        }
      }
      __syncthreads();
    }
    #pragma unroll
    for (int w = 0; w < 16; ++w) {
      float iv = sigf(acc0[w]), fv = sigf(acc1[w]);
      float gv = tanhf(acc2[w]), ov = sigf(acc3[w]);
      c[w] = fv * c[w] + iv * gv;
      float h = ov * tanhf(c[w]);
      u[w][256 + ch] = h;
      if (t == sidx[w]) word_emb[(size_t)(w0 + w) * 256 + ch] = h;
    }
  }
}

// ---------------- generic fp32 GEMM: C = act(A @ B^T + bias)
// PERM=1: write col n at permuted position (n&511)*4 + (n>>9)  (unit-major x).
template <int SPLIT, int ACT, int PERM>
__global__ __launch_bounds__(256) void gemm_kernel(
    const float* __restrict__ A, const float* __restrict__ A2,
    const float* __restrict__ B, const float* __restrict__ bias,
    float* __restrict__ C, int M, int N, int K)
{
  __shared__ float At[8][132];
  __shared__ float Bt[8][132];
  const int tid = threadIdx.x;
  const int bm0 = blockIdx.x * 128, bn0 = blockIdx.y * 128;
  float acc[8][8];
  #pragma unroll
  for (int i = 0; i < 8; ++i)
    #pragma unroll
    for (int j = 0; j < 8; ++j) acc[i][j] = 0.f;
  const int sr = tid >> 1;
  const int sk = (tid & 1) * 4;
  const int tm = (tid >> 4) * 8, tn = (tid & 15) * 8;
  for (int k0 = 0; k0 < K; k0 += 8) {
    const int kg = k0 + sk;
    float4 av;
    if (SPLIT) {
      const float* srcp = (kg < 512) ? A : A2;
      av = *(const float4*)(srcp + (size_t)(bm0 + sr) * 512 + (kg & 511));
    } else {
      av = *(const float4*)(A + (size_t)(bm0 + sr) * K + kg);
    }
    float4 bv = {0.f, 0.f, 0.f, 0.f};
    if (bn0 + sr < N) bv = *(const float4*)(B + (size_t)(bn0 + sr) * K + kg);
    At[sk + 0][sr] = av.x; At[sk + 1][sr] = av.y; At[sk + 2][sr] = av.z; At[sk + 3][sr] = av.w;
    Bt[sk + 0][sr] = bv.x; Bt[sk + 1][sr] = bv.y; Bt[sk + 2][sr] = bv.z; Bt[sk + 3][sr] = bv.w;
    __syncthreads();
    #pragma unroll
    for (int kk = 0; kk < 8; ++kk) {
      float a[8], b[8];
      *(float4*)&a[0] = *(const float4*)&At[kk][tm];
      *(float4*)&a[4] = *(const float4*)&At[kk][tm + 4];
      *(float4*)&b[0] = *(const float4*)&Bt[kk][tn];
      *(float4*)&b[4] = *(const float4*)&Bt[kk][tn + 4];
      #pragma unroll
      for (int i = 0; i < 8; ++i)
        #pragma unroll
        for (int j = 0; j < 8; ++j) acc[i][j] = fmaf(a[i], b[j], acc[i][j]);
    }
    __syncthreads();
  }
  #pragma unroll
  for (int i = 0; i < 8; ++i) {
    const int m = bm0 + tm + i;
    float* crow = C + (size_t)m * N;
    #pragma unroll
    for (int j = 0; j < 8; ++j) {
      const int n = bn0 + tn + j;
      if (n < N) {
        float v = acc[i][j] + bias[n];
        if (ACT) v = tanhf(v);
        if (PERM) crow[((n & 511) << 2) | (n >> 9)] = v;
        else      crow[n] = v;
      }
    }
  }
}

// ---------------- persistent bidirectional scan v4 (1 wave / WG, no barriers)
// X is unit-major permuted: X[p*2048 + j*4 + g]  (g = i,f,g,o).
__global__ __launch_bounds__(64) void scan_kernel(
    const float* __restrict__ Xf, const float* __restrict__ Xb,
    const float* __restrict__ Whf, const float* __restrict__ Whb,
    unsigned long long* __restrict__ Tf, unsigned long long* __restrict__ Tb,
    float* __restrict__ Hf, float* __restrict__ Hb)
{
  const int bid = blockIdx.x;
  const int dir = bid >> 8;            // 256 WGs per dir
  const int wg  = bid & 255;
  const int lane = threadIdx.x;        // 0..63
  const int j0 = wg * 2;               // two hidden units per WG
  const float* X = dir ? Xb : Xf;
  const float* Wh = dir ? Whb : Whf;
  unsigned long long* T = dir ? Tb : Tf;
  float* Hd = dir ? Hb : Hf;

  // weights: w[u][g][i], k-slice = lane*8 + i
  float w[2][4][8];
  #pragma unroll
  for (int u = 0; u < 2; ++u)
    #pragma unroll
    for (int g = 0; g < 4; ++g) {
      const float* wr = Wh + ((size_t)(g * 512 + j0 + u)) * 512 + lane * 8;
      *(float4*)&w[u][g][0] = *(const float4*)wr;
      *(float4*)&w[u][g][4] = *(const float4*)(wr + 4);
    }

  float4 xc = {0,0,0,0}, xn = {0,0,0,0};
  if (lane < 2) {
    xc = *(const float4*)&X[(size_t)(dir ? NPOS - 1 : 0) * GDIM + (j0 + lane) * 4];
    xn = *(const float4*)&X[(size_t)(dir ? NPOS - 2 : 1) * GDIM + (j0 + lane) * 4];
  }
  float creg = 0.f;

  for (int s = 0; s < NPOS; ++s) {
    const int p = dir ? (NPOS - 1 - s) : s;
    float s00 = 0.f, s01 = 0.f, s02 = 0.f, s03 = 0.f;
    float s10 = 0.f, s11 = 0.f, s12 = 0.f, s13 = 0.f;

    if (s > 0) {
      const unsigned int tg = (unsigned int)s;
      const unsigned long long* bp = T + (size_t)((s - 1) & 1) * 512 + lane * 8;
      uint4v q0, q1, q2, q3;
      bool ok;
      do {
        asm volatile(
            "global_load_dwordx4 %0, %4, off sc0 sc1\n\t"
            "global_load_dwordx4 %1, %4, off offset:16 sc0 sc1\n\t"
            "global_load_dwordx4 %2, %4, off offset:32 sc0 sc1\n\t"
            "global_load_dwordx4 %3, %4, off offset:48 sc0 sc1\n\t"
            "s_waitcnt vmcnt(0)"
            : "=&v"(q0), "=&v"(q1), "=&v"(q2), "=&v"(q3)
            : "v"(bp)
            : "memory");
        ok = (q0.y == tg) & (q0.w == tg) & (q1.y == tg) & (q1.w == tg)
           & (q2.y == tg) & (q2.w == tg) & (q3.y == tg) & (q3.w == tg);
      } while (!ok);
      float hk[8];
      hk[0] = __uint_as_float(q0.x); hk[1] = __uint_as_float(q0.z);
      hk[2] = __uint_as_float(q1.x); hk[3] = __uint_as_float(q1.z);
      hk[4] = __uint_as_float(q2.x); hk[5] = __uint_as_float(q2.z);
      hk[6] = __uint_as_float(q3.x); hk[7] = __uint_as_float(q3.z);
      #pragma unroll
      for (int i = 0; i < 8; ++i) {
        const float hv = hk[i];
        s00 = fmaf(w[0][0][i], hv, s00);
        s01 = fmaf(w[0][1][i], hv, s01);
        s02 = fmaf(w[0][2][i], hv, s02);
        s03 = fmaf(w[0][3][i], hv, s03);
        s10 = fmaf(w[1][0][i], hv, s10);
        s11 = fmaf(w[1][1][i], hv, s11);
        s12 = fmaf(w[1][2][i], hv, s12);
        s13 = fmaf(w[1][3][i], hv, s13);
      }
    }

    // issue x prefetch for step s+2 early (returns under reduce/nonlin)
    float4 xnn = {0, 0, 0, 0};
    if (lane < 2 && s + 2 < NPOS) {
      const int p2 = dir ? (NPOS - 3 - s) : (s + 2);
      xnn = *(const float4*)&X[(size_t)p2 * GDIM + (j0 + lane) * 4];
    }

    // wave butterfly: all lanes end with full sums
    #pragma unroll
    for (int m = 1; m < 64; m <<= 1) {
      s00 += __shfl_xor(s00, m); s01 += __shfl_xor(s01, m);
      s02 += __shfl_xor(s02, m); s03 += __shfl_xor(s03, m);
      s10 += __shfl_xor(s10, m); s11 += __shfl_xor(s11, m);
      s12 += __shfl_xor(s12, m); s13 += __shfl_xor(s13, m);
    }

    if (lane < 2) {
      const float gi = (lane ? s10 : s00) + xc.x;
      const float gf = (lane ? s11 : s01) + xc.y;
      const float gc = (lane ? s12 : s02) + xc.z;
      const float go = (lane ? s13 : s03) + xc.w;
      const float iv = sigf(gi), fv = sigf(gf);
      const float gv = tanh_fast(gc), ov = sigf(go);
      creg = fv * creg + iv * gv;
      const float h = ov * tanh_fast(creg);
      const int j = j0 + lane;
      unsigned long long pack = ((unsigned long long)(unsigned int)(s + 1) << 32)
                              | (unsigned long long)__float_as_uint(h);
      __hip_atomic_store(&T[(size_t)(s & 1) * 512 + j], pack,
                         __ATOMIC_RELAXED, __HIP_MEMORY_SCOPE_AGENT);
      Hd[(size_t)p * 512 + j] = h;
      xc = xn; xn = xnn;
    }
  }
}

extern "C" void kernel_launch(void* const* d_in, const int* in_sizes, int n_in,
                              void* d_out, int out_size, void* d_ws, size_t ws_size,
                              hipStream_t stream) {
  const int* chars = (const int*)d_in[0];
  const int* lens = (const int*)d_in[1];
  const float* table = (const float*)d_in[2];
  const float* cWih = (const float*)d_in[3];
  const float* cWhh = (const float*)d_in[4];
  const float* cb = (const float*)d_in[5];
  const float* Wih0 = (const float*)d_in[6];   // [2][2048][256]
  const float* Whh0 = (const float*)d_in[7];   // [2][2048][512]
  const float* b0 = (const float*)d_in[8];
  const float* Wih1 = (const float*)d_in[9];   // [2][2048][1024]
  const float* Whh1 = (const float*)d_in[10];  // [2][2048][512]
  const float* b1 = (const float*)d_in[11];
  const float* fc1w = (const float*)d_in[12];
  const float* fc1b = (const float*)d_in[13];
  const float* fc2w = (const float*)d_in[14];
  const float* fc2b = (const float*)d_in[15];
  float* out = (float*)d_out;

  char* ws = (char*)d_ws;
  size_t off = 0;
  auto alloc = [&](size_t bytes) -> void* {
    void* p = ws + off;
    off += (bytes + 255) & ~(size_t)255;
    return p;
  };
  float* word_emb = (float*)alloc((size_t)4096 * 256 * 4);
  float* X0f = (float*)alloc((size_t)4096 * 2048 * 4);
  float* X0b = (float*)alloc((size_t)4096 * 2048 * 4);
  float* H0f = (float*)alloc((size_t)4096 * 512 * 4);
  float* H0b = (float*)alloc((size_t)4096 * 512 * 4);
  float* H1f = (float*)alloc((size_t)4096 * 512 * 4);
  float* H1b = (float*)alloc((size_t)4096 * 512 * 4);
  float* fc1out = (float*)alloc((size_t)4096 * 512 * 4);
  float* Wt = (float*)alloc((size_t)512 * 1024 * 4);
  unsigned long long* Tall = (unsigned long long*)alloc((size_t)4 * 1024 * 8);  // 4 rings x 2 slots x 512
  unsigned long long* T0f = Tall;
  unsigned long long* T0b = Tall + 1024;
  unsigned long long* T1f = Tall + 2048;
  unsigned long long* T1b = Tall + 3072;
  if (off > ws_size) return;

  // clear tag rings (inside graph -> every replay re-synchronizes honestly)
  hipMemsetAsync(Tall, 0, (size_t)4 * 1024 * 8, stream);

  build_wt_kernel<<<dim3(8, 16), 256, 0, stream>>>(cWih, cWhh, Wt);
  char_lstm_kernel<<<256, 256, 0, stream>>>(chars, lens, table, Wt, cb, word_emb);

  gemm_kernel<0, 0, 1><<<dim3(32, 16), 256, 0, stream>>>(
      word_emb, nullptr, Wih0, b0, X0f, 4096, 2048, 256);
  gemm_kernel<0, 0, 1><<<dim3(32, 16), 256, 0, stream>>>(
      word_emb, nullptr, Wih0 + (size_t)2048 * 256, b0 + 2048, X0b, 4096, 2048, 256);
  scan_kernel<<<512, 64, 0, stream>>>(X0f, X0b, Whh0, Whh0 + (size_t)2048 * 512,
                                      T0f, T0b, H0f, H0b);

  gemm_kernel<1, 0, 1><<<dim3(32, 16), 256, 0, stream>>>(
      H0f, H0b, Wih1, b1, X0f, 4096, 2048, 1024);
  gemm_kernel<1, 0, 1><<<dim3(32, 16), 256, 0, stream>>>(
      H0f, H0b, Wih1 + (size_t)2048 * 1024, b1 + 2048, X0b, 4096, 2048, 1024);
  scan_kernel<<<512, 64, 0, stream>>>(X0f, X0b, Whh1, Whh1 + (size_t)2048 * 512,
                                      T1f, T1b, H1f, H1b);

  gemm_kernel<1, 1, 0><<<dim3(32, 4), 256, 0, stream>>>(
      H1f, H1b, fc1w, fc1b, fc1out, 4096, 512, 1024);
  gemm_kernel<0, 0, 0><<<dim3(32, 1), 256, 0, stream>>>(
      fc1out, nullptr, fc2w, fc2b, out, 4096, 50, 512);
}